// Round 15
// baseline (361.445 us; speedup 1.0000x reference)
//
#include <hip/hip_runtime.h>
#include <hip/hip_bf16.h>

#define NCLS   100000
#define NPAD   100096   // 391 * 256
#define BATCH  1024
#define EDIM   512

#define COS_M_  0.8775825618903728f
#define SIN_M_  0.479425538604203f
#define TH_     (-0.8775825618903728f)
#define MM_     0.2397127693021015f
#define SCALE_  64.0f

typedef __attribute__((ext_vector_type(8))) short short8;
typedef __attribute__((ext_vector_type(4))) float f32x4;

__device__ __forceinline__ ushort f2bf(float f) {
    // round-to-nearest-even f32 -> bf16
    uint u = __float_as_uint(f);
    u += 0x7fffu + ((u >> 16) & 1u);
    return (ushort)(u >> 16);
}

// One 64-lane wave per row: L2-normalize 512 f32 -> 512 bf16.
// Handles BOTH inputs in one launch: global wave id gw < BATCH -> emb row,
// else W row gw-BATCH (rows >= NCLS zero-filled for N-padding).
__global__ __launch_bounds__(256) void norm_all_kernel(
    const float* __restrict__ emb, const float* __restrict__ wgt,
    ushort* __restrict__ Ebf, ushort* __restrict__ Wbf)
{
    int gw   = (int)((blockIdx.x * blockDim.x + threadIdx.x) >> 6);
    int lane = (int)(threadIdx.x & 63);
    const float* ip;
    ushort* op;
    if (gw < BATCH) {
        ip = emb + (size_t)gw * EDIM + lane * 8;
        op = Ebf + (size_t)gw * EDIM + lane * 8;
    } else {
        int wr = gw - BATCH;
        if (wr >= NPAD) return;
        op = Wbf + (size_t)wr * EDIM + lane * 8;
        if (wr >= NCLS) {
            uint4 z = make_uint4(0u, 0u, 0u, 0u);
            *(uint4*)op = z;
            return;
        }
        ip = wgt + (size_t)wr * EDIM + lane * 8;
    }
    float4 x0 = *(const float4*)ip;
    float4 x1 = *(const float4*)(ip + 4);
    float ss = x0.x*x0.x + x0.y*x0.y + x0.z*x0.z + x0.w*x0.w
             + x1.x*x1.x + x1.y*x1.y + x1.z*x1.z + x1.w*x1.w;
    #pragma unroll
    for (int off = 32; off; off >>= 1) ss += __shfl_xor(ss, off, 64);
    float inv = 1.0f / fmaxf(sqrtf(ss), 1e-12f);
    uint w0 = (uint)f2bf(x0.x*inv) | ((uint)f2bf(x0.y*inv) << 16);
    uint w1 = (uint)f2bf(x0.z*inv) | ((uint)f2bf(x0.w*inv) << 16);
    uint w2 = (uint)f2bf(x1.x*inv) | ((uint)f2bf(x1.y*inv) << 16);
    uint w3 = (uint)f2bf(x1.z*inv) | ((uint)f2bf(x1.w*inv) << 16);
    uint4 r; r.x = w0; r.y = w1; r.z = w2; r.w = w3;
    *(uint4*)op = r;
}

// Margin fixup: only the 1024 (row, label[row]) entries need the ArcFace
// margin. GEMM stored clamp(cos)*64; recover cos = v/64 (exact, pow2 scale),
// apply margin, rewrite.
__global__ __launch_bounds__(256) void fixup_labels_kernel(
    const int* __restrict__ labels, float* __restrict__ C)
{
    int row = (int)(blockIdx.x * blockDim.x + threadIdx.x);
    if (row >= BATCH) return;
    int lab = labels[row];
    float* p = C + (size_t)row * NCLS + lab;
    float c = *p * (1.0f / SCALE_);
    float s  = sqrtf(1.0f - c * c);
    float cm = c * COS_M_ - s * SIN_M_;
    cm = (c > TH_) ? cm : (c - MM_);
    *p = cm * SCALE_;
}

#define GLL16(g, s) __builtin_amdgcn_global_load_lds(                    \
    (const __attribute__((address_space(1))) void*)(g),                  \
    (__attribute__((address_space(3))) void*)(s), 16, 0, 0)

// 128(M)x256(N) block tile, BK=32, 4 waves (2M x 2N), WAVE TILE 64x128:
// acc[4][8] -> 32 MFMA per wave per K-step = 2x FLOP per barrier-pair vs the
// 64x64 wave tile (per-FLOP sync overhead was the residual). SWAPPED-operand
// mfma (lane's 4 acc regs = 4 consecutive N-cols). Depth-2 double-buffered
// LDS (48 KB -> 3 blocks/CU), counted vmcnt(6) + raw s_barrier (tile kt+1's
// 6 loads stay in flight across barriers). XOR-swizzled K-slots, T1 XCD
// chunk swizzle. LDS-transposed epilogue (R14): C staged through LDS in 4
// chunks of 32x256, NT-stored as full 128-B lines (no partial-line write
// amplification; NT essential — plain stores evict B from L2, R10 +64us).
__global__ __launch_bounds__(256, 3) void gemm_arc_kernel(
    const ushort* __restrict__ A,
    const ushort* __restrict__ B,
    float* __restrict__ C)
{
    // A bufs at 0/8192 (8 KB each); B bufs at 16384/32768 (16 KB each).
    // Epilogue reuses [0..32768) as a [32][256] f32 chunk buffer.
    __shared__ __align__(16) char smem[49152];

    const int t    = (int)threadIdx.x;
    const int lane = t & 63;
    const int w    = t >> 6;
    const int wrow = w >> 1, wcol = w & 1;   // 2M x 2N; wave tile 64M x 128N
    const int lr   = lane & 15, lg = lane >> 4;

    // T1 bijective XCD swizzle: the 8 M-blocks sharing a B-panel land on ONE
    // XCD. nwg = 3128, %8 == 0.
    const int nwg  = (int)gridDim.x;
    const int cpx  = nwg >> 3;               // 391
    const int bid  = (int)blockIdx.x;
    const int swz  = (bid & 7) * cpx + (bid >> 3);
    const int brow = swz & 7;                // M-tile (0..7)
    const int bcol = swz >> 3;               // N-tile (0..390)

    const f32x4 z4 = {0.f, 0.f, 0.f, 0.f};
    f32x4 acc[4][8];
    #pragma unroll
    for (int i = 0; i < 4; ++i)
        #pragma unroll
        for (int j = 0; j < 8; ++j) acc[i][j] = z4;

    // staging: one GLL line = 256 thr x 16 B = 4 KB = 64 rows x 64 B.
    // A tile 128 rows -> 2 lines; B tile 256 rows -> 4 lines. LDS dest
    // linear; global SOURCE byte offset carries the inverse K-slot swizzle
    // off' ^= ((row>>1)&3)<<4 (row-chunk offsets 64/128/192 are 0 mod 4
    // after >>1, so one swizzled base serves all lines).
    const int srow = t >> 2;
    const int scb  = ((t & 3) * 16) ^ (((t >> 3) & 3) << 4);
    const char* Ab = (const char*)(A + ((size_t)brow * 128 + srow) * EDIM) + scb;
    const char* Bb = (const char*)(B + ((size_t)bcol * 256 + srow) * EDIM) + scb;
    const uint ldsw = (uint)w * 1024;        // wave-uniform LDS base (+lane*16 HW)

    // ds_read side: row R = base16 + lr, byte (lg*16) ^ ((R>>1)&3)<<4; the
    // XOR term is the per-lane constant ((lr>>1)&3)<<4.
    const int kswz  = ((lr >> 1) & 3) << 4;
    const int aoff0 = (wrow * 64  + lr) * 64 + ((lg * 16) ^ kswz);
    const int boff0 = (wcol * 128 + lr) * 64 + ((lg * 16) ^ kswz);

#define STAGE(c, kt) do {                                                  \
        const char* a0 = Ab + (kt) * 64;                                   \
        const char* b0 = Bb + (kt) * 64;                                   \
        char* Ad = smem + (size_t)(c) * 8192 + ldsw;                       \
        char* Bd = smem + 16384 + (size_t)(c) * 16384 + ldsw;              \
        GLL16(a0,               Ad);                                       \
        GLL16(a0 +  64 * 1024,  Ad + 4096);                                \
        GLL16(b0,               Bd);                                       \
        GLL16(b0 +  64 * 1024,  Bd + 4096);                                \
        GLL16(b0 + 128 * 1024,  Bd + 8192);                                \
        GLL16(b0 + 192 * 1024,  Bd + 12288);                               \
    } while (0)

// Swapped operands: mfma(bv, av) -> acc[mi][ni][reg] =
//   C[brow*128 + wrow*64 + mi*16 + lr][bcol*256 + wcol*128 + ni*16 + lg*4 + reg]
#define COMPUTE(c) do {                                                    \
        const char* Ap = (const char*)smem + (size_t)(c) * 8192;           \
        const char* Bp = (const char*)smem + 16384 + (size_t)(c) * 16384;  \
        short8 av[4], bv[8];                                               \
        _Pragma("unroll")                                                  \
        for (int mi = 0; mi < 4; ++mi)                                     \
            av[mi] = *(const short8*)(Ap + aoff0 + mi * 1024);             \
        _Pragma("unroll")                                                  \
        for (int ni = 0; ni < 8; ++ni)                                     \
            bv[ni] = *(const short8*)(Bp + boff0 + ni * 1024);             \
        _Pragma("unroll")                                                  \
        for (int mi = 0; mi < 4; ++mi)                                     \
            _Pragma("unroll")                                              \
            for (int ni = 0; ni < 8; ++ni)                                 \
                acc[mi][ni] = __builtin_amdgcn_mfma_f32_16x16x32_bf16(     \
                    bv[ni], av[mi], acc[mi][ni], 0, 0, 0);                 \
    } while (0)

    // prologue: stage tile 0 (6 loads in flight)
    STAGE(0, 0);

    // main loop: stage kt+1 into the other buffer, wait ONLY for tile kt
    // (vmcnt(6) leaves tile kt+1's 6 loads in flight across the barrier),
    // compute kt. Buffer (kt+1)&1 was last read in COMPUTE(kt-1), protected
    // by the leading lgkm0+barrier.
    #pragma unroll
    for (int kt = 0; kt < 15; ++kt) {
        asm volatile("s_waitcnt lgkmcnt(0)" ::: "memory");
        __builtin_amdgcn_s_barrier();
        STAGE((kt + 1) & 1, kt + 1);
        asm volatile("s_waitcnt vmcnt(6)" ::: "memory");
        __builtin_amdgcn_s_barrier();
        COMPUTE(kt & 1);
    }
    // tail: tile 15 already staged; drain
    asm volatile("s_waitcnt vmcnt(0)" ::: "memory");
    __builtin_amdgcn_s_barrier();
    COMPUTE(15 & 1);

    // ---- LDS-transposed epilogue, 4 chunks of 32 rows x 256 cols (32 KB) --
    // Chunk (h,g): rows brow*128 + h*64 + g*32 .. +32, all 256 cols. Writers:
    // waves (h,0),(h,1) ds_write their clamp+scaled fragments mi in {2g,2g+1}
    // at slot' = slot ^ (row&7) (bank spread). All 256 threads then read back
    // and NT-store full 128-B lines (8 per thread).
    asm volatile("s_waitcnt lgkmcnt(0)" ::: "memory");
    __builtin_amdgcn_s_barrier();            // all waves done with A/B LDS

    const int mbase = brow * 128;
    const size_t cb = (size_t)bcol * 1024;   // C col byte base (256 cols f32)
    const int rowl  = t >> 3;                // 0..31 readout row
    const int sbase = t & 7;                 // readout slot base

    #pragma unroll
    for (int h = 0; h < 2; ++h) {
        #pragma unroll
        for (int g = 0; g < 2; ++g) {
            if (wrow == h) {
                #pragma unroll
                for (int m2 = 0; m2 < 2; ++m2) {
                    const int mi = g * 2 + m2;
                    const int r  = m2 * 16 + lr;         // row in chunk 0..31
                    #pragma unroll
                    for (int ni = 0; ni < 8; ++ni) {
                        const int s = wcol * 32 + ni * 4 + lg;  // 16B slot 0..63
                        f32x4 v = acc[mi][ni];
                        f32x4 o;
                        #pragma unroll
                        for (int j = 0; j < 4; ++j) {
                            float cc = fminf(fmaxf(v[j], -1.0f + 1e-7f),
                                             1.0f - 1e-7f);
                            o[j] = cc * SCALE_;
                        }
                        *(f32x4*)(smem + (size_t)r * 1024
                                  + (size_t)((s ^ (r & 7)) * 16)) = o;
                    }
                }
            }
            asm volatile("s_waitcnt lgkmcnt(0)" ::: "memory");
            __builtin_amdgcn_s_barrier();
            #pragma unroll
            for (int p = 0; p < 8; ++p) {
                const int s = sbase + 8 * p;
                if (bcol * 256 + s * 4 < NCLS) {          // NCLS % 4 == 0
                    f32x4 v = *(const f32x4*)(smem + (size_t)rowl * 1024
                              + (size_t)((s ^ (rowl & 7)) * 16));
                    const int grow = mbase + h * 64 + g * 32 + rowl;
                    __builtin_nontemporal_store(v,
                        (f32x4*)((char*)C + (size_t)grow * (NCLS * 4)
                                 + cb + (size_t)s * 16));
                }
            }
            if (!(h == 1 && g == 1)) {
                asm volatile("s_waitcnt lgkmcnt(0)" ::: "memory");
                __builtin_amdgcn_s_barrier();  // reads done before next writers
            }
        }
    }
#undef STAGE
#undef COMPUTE
}

extern "C" void kernel_launch(void* const* d_in, const int* in_sizes, int n_in,
                              void* d_out, int out_size, void* d_ws, size_t ws_size,
                              hipStream_t stream)
{
    const float* emb    = (const float*)d_in[0];
    const int*   labels = (const int*)d_in[1];
    const float* wgt    = (const float*)d_in[2];
    float*       out    = (float*)d_out;

    // workspace layout: [Ebf: 1024*512 bf16 = 1 MB][Wbf: 100096*512 bf16 = 102.5 MB]
    ushort* Ebf = (ushort*)d_ws;
    ushort* Wbf = (ushort*)((char*)d_ws + (size_t)BATCH * EDIM * 2);

    norm_all_kernel<<<(BATCH + NPAD) / 4, 256, 0, stream>>>(emb, wgt, Ebf, Wbf);

    gemm_arc_kernel<<<(BATCH / 128) * (NPAD / 256), 256, 0, stream>>>(Ebf, Wbf, out);

    fixup_labels_kernel<<<BATCH / 256, 256, 0, stream>>>(labels, out);
}

// Round 16
// 204.109 us; speedup vs baseline: 1.7708x; 1.7708x over previous
//
#include <hip/hip_runtime.h>
#include <hip/hip_bf16.h>

#define NCLS   100000
#define NPAD   100096   // 782 * 128
#define BATCH  1024
#define EDIM   512

#define COS_M_  0.8775825618903728f
#define SIN_M_  0.479425538604203f
#define TH_     (-0.8775825618903728f)
#define MM_     0.2397127693021015f
#define SCALE_  64.0f

typedef __attribute__((ext_vector_type(8))) short short8;
typedef __attribute__((ext_vector_type(4))) float f32x4;

__device__ __forceinline__ ushort f2bf(float f) {
    // round-to-nearest-even f32 -> bf16
    uint u = __float_as_uint(f);
    u += 0x7fffu + ((u >> 16) & 1u);
    return (ushort)(u >> 16);
}

// One 64-lane wave per row: L2-normalize 512 f32 -> 512 bf16.
// Handles BOTH inputs in one launch: global wave id gw < BATCH -> emb row,
// else W row gw-BATCH (rows >= NCLS zero-filled for N-padding).
// NT loads: the f32 inputs are read exactly once — keep them from
// allocating L3 so the bf16 outputs (which the GEMM re-reads) stay resident.
__global__ __launch_bounds__(256) void norm_all_kernel(
    const float* __restrict__ emb, const float* __restrict__ wgt,
    ushort* __restrict__ Ebf, ushort* __restrict__ Wbf)
{
    int gw   = (int)((blockIdx.x * blockDim.x + threadIdx.x) >> 6);
    int lane = (int)(threadIdx.x & 63);
    const float* ip;
    ushort* op;
    if (gw < BATCH) {
        ip = emb + (size_t)gw * EDIM + lane * 8;
        op = Ebf + (size_t)gw * EDIM + lane * 8;
    } else {
        int wr = gw - BATCH;
        if (wr >= NPAD) return;
        op = Wbf + (size_t)wr * EDIM + lane * 8;
        if (wr >= NCLS) {
            uint4 z = make_uint4(0u, 0u, 0u, 0u);
            *(uint4*)op = z;
            return;
        }
        ip = wgt + (size_t)wr * EDIM + lane * 8;
    }
    f32x4 x0 = __builtin_nontemporal_load((const f32x4*)ip);
    f32x4 x1 = __builtin_nontemporal_load((const f32x4*)(ip + 4));
    float ss = x0[0]*x0[0] + x0[1]*x0[1] + x0[2]*x0[2] + x0[3]*x0[3]
             + x1[0]*x1[0] + x1[1]*x1[1] + x1[2]*x1[2] + x1[3]*x1[3];
    #pragma unroll
    for (int off = 32; off; off >>= 1) ss += __shfl_xor(ss, off, 64);
    float inv = 1.0f / fmaxf(sqrtf(ss), 1e-12f);
    uint w0 = (uint)f2bf(x0[0]*inv) | ((uint)f2bf(x0[1]*inv) << 16);
    uint w1 = (uint)f2bf(x0[2]*inv) | ((uint)f2bf(x0[3]*inv) << 16);
    uint w2 = (uint)f2bf(x1[0]*inv) | ((uint)f2bf(x1[1]*inv) << 16);
    uint w3 = (uint)f2bf(x1[2]*inv) | ((uint)f2bf(x1[3]*inv) << 16);
    uint4 r; r.x = w0; r.y = w1; r.z = w2; r.w = w3;
    *(uint4*)op = r;   // normal store: keep Wbf in L2/L3 for the GEMM
}

// Margin fixup: only the 1024 (row, label[row]) entries need the ArcFace
// margin. GEMM stored clamp(cos)*64; recover cos = v/64 (exact, pow2 scale),
// apply margin, rewrite.
__global__ __launch_bounds__(256) void fixup_labels_kernel(
    const int* __restrict__ labels, float* __restrict__ C)
{
    int row = (int)(blockIdx.x * blockDim.x + threadIdx.x);
    if (row >= BATCH) return;
    int lab = labels[row];
    float* p = C + (size_t)row * NCLS + lab;
    float c = *p * (1.0f / SCALE_);
    float s  = sqrtf(1.0f - c * c);
    float cm = c * COS_M_ - s * SIN_M_;
    cm = (c > TH_) ? cm : (c - MM_);
    *p = cm * SCALE_;
}

#define GLL16(g, s) __builtin_amdgcn_global_load_lds(                    \
    (const __attribute__((address_space(1))) void*)(g),                  \
    (__attribute__((address_space(3))) void*)(s), 16, 0, 0)

// 128x128 tile, BK=32, 4 waves (2x2), mfma_f32_16x16x32_bf16 (SWAPPED
// operands: lane's 4 acc regs = 4 consecutive N-cols). Depth-2 double-
// buffered LDS (32 KB -> 4 blocks/CU), counted vmcnt + raw s_barrier.
// XOR-swizzled K-slots, T1 XCD chunk swizzle. LDS-transposed epilogue —
// C half-tiles staged through the (now free) 32 KB LDS and NT-stored as
// fully line-covered contiguous 4 KB spans (kills the 1.42x partial-line
// write amplification of direct per-fragment NT stores; NT itself must stay:
// plain stores evict B panels from L2, +64us measured R10).
__global__ __launch_bounds__(256, 4) void gemm_arc_kernel(
    const ushort* __restrict__ A,
    const ushort* __restrict__ B,
    float* __restrict__ C)
{
    // A buffers at +0/+8192; B buffers at +16384/+24576. Reused as a
    // [64][128] f32 C-staging buffer (32 KB) in the epilogue.
    __shared__ __align__(16) char smem[32768];

    const int t    = (int)threadIdx.x;
    const int lane = t & 63;
    const int w    = t >> 6;
    const int wrow = w >> 1, wcol = w & 1;
    const int lr   = lane & 15, lg = lane >> 4;

    // T1 bijective XCD swizzle: the 8 M-blocks sharing a B-tile land on ONE
    // XCD. nwg = 6256, %8 == 0.
    const int nwg  = (int)gridDim.x;
    const int cpx  = nwg >> 3;               // 782
    const int bid  = (int)blockIdx.x;
    const int swz  = (bid & 7) * cpx + (bid >> 3);
    const int brow = swz & 7;                // M-tile (0..7)
    const int bcol = swz >> 3;               // N-tile (0..781)

    const f32x4 z4 = {0.f, 0.f, 0.f, 0.f};
    f32x4 acc[4][4];
    #pragma unroll
    for (int i = 0; i < 4; ++i)
        #pragma unroll
        for (int j = 0; j < 4; ++j) acc[i][j] = z4;

    // staging: 256 threads x 16 B = 4 KB per instruction = 64 rows x 64 B.
    // LDS dest linear; global SOURCE byte offset carries the inverse K-slot
    // swizzle off' ^= ((row>>1)&3)<<4.
    const int srow = t >> 2;
    const int scb  = ((t & 3) * 16) ^ (((t >> 3) & 3) << 4);
    const char* Ab = (const char*)(A + ((size_t)brow * 128 + srow) * EDIM) + scb;
    const char* Bb = (const char*)(B + ((size_t)bcol * 128 + srow) * EDIM) + scb;
    const uint ldsw = (uint)w * 1024;        // wave-uniform LDS base (+lane*16 HW)

    // ds_read side: row R, byte (lg*16) ^ ((R>>1)&3)<<4; for R = base16+lr the
    // XOR term is the per-lane constant ((lr>>1)&3)<<4.
    const int kswz  = ((lr >> 1) & 3) << 4;
    const int aoff0 = (wrow * 64 + lr) * 64 + ((lg * 16) ^ kswz);
    const int boff0 = (wcol * 64 + lr) * 64 + ((lg * 16) ^ kswz);

#define STAGE(c, kt) do {                                                  \
        const char* a0 = Ab + (kt) * 64;                                   \
        const char* b0 = Bb + (kt) * 64;                                   \
        char* Ad = smem + (size_t)(c) * 8192 + ldsw;                       \
        char* Bd = smem + 16384 + (size_t)(c) * 8192 + ldsw;               \
        GLL16(a0,                 Ad);                                     \
        GLL16(a0 + 64 * EDIM * 2, Ad + 4096);                              \
        GLL16(b0,                 Bd);                                     \
        GLL16(b0 + 64 * EDIM * 2, Bd + 4096);                              \
    } while (0)

// Swapped operands: mfma(bv, av) -> acc[mi][ni][reg] =
//   C[brow*128 + wrow*64 + mi*16 + lr][bcol*128 + wcol*64 + ni*16 + lg*4 + reg]
#define COMPUTE(c) do {                                                    \
        const char* Ap = (const char*)smem + (size_t)(c) * 8192;           \
        const char* Bp = (const char*)smem + 16384 + (size_t)(c) * 8192;   \
        short8 av[4], bv[4];                                               \
        _Pragma("unroll")                                                  \
        for (int mi = 0; mi < 4; ++mi)                                     \
            av[mi] = *(const short8*)(Ap + aoff0 + mi * 1024);             \
        _Pragma("unroll")                                                  \
        for (int ni = 0; ni < 4; ++ni)                                     \
            bv[ni] = *(const short8*)(Bp + boff0 + ni * 1024);             \
        _Pragma("unroll")                                                  \
        for (int mi = 0; mi < 4; ++mi)                                     \
            _Pragma("unroll")                                              \
            for (int ni = 0; ni < 4; ++ni)                                 \
                acc[mi][ni] = __builtin_amdgcn_mfma_f32_16x16x32_bf16(     \
                    bv[ni], av[mi], acc[mi][ni], 0, 0, 0);                 \
    } while (0)

    // prologue: stage tile 0 (4 loads in flight)
    STAGE(0, 0);

    // main loop: stage kt+1 into the other buffer, wait ONLY for tile kt
    // (vmcnt(4) leaves tile kt+1's 4 loads in flight across the barrier),
    // compute kt.
    #pragma unroll
    for (int kt = 0; kt < 15; ++kt) {
        asm volatile("s_waitcnt lgkmcnt(0)" ::: "memory");
        __builtin_amdgcn_s_barrier();
        STAGE((kt + 1) & 1, kt + 1);
        asm volatile("s_waitcnt vmcnt(4)" ::: "memory");
        __builtin_amdgcn_s_barrier();
        COMPUTE(kt & 1);
    }
    // tail: tile 15 already staged; drain
    asm volatile("s_waitcnt vmcnt(0)" ::: "memory");
    __builtin_amdgcn_s_barrier();
    COMPUTE(15 & 1);

    // ---- LDS-transposed epilogue ----
    // Half h = rows wrow==h (64 rows x 128 cols f32 = 32 KB). Waves of that
    // half ds_write clamp+scaled fragments at slot' = slot ^ (row&7)
    // (banks spread 8-way -> 2-way aliasing, free). All threads then read
    // back linearly and NT-store contiguous 4 KB per instruction (complete
    // 128-B lines -> no partial-line write amplification).
    asm volatile("s_waitcnt lgkmcnt(0)" ::: "memory");
    __builtin_amdgcn_s_barrier();            // all waves done with A/B LDS

    const int mbase = brow * 128;
    const size_t cb = (size_t)bcol * 512;    // C col byte base
    const int rowl = t >> 5;                 // 0..7 (readout row-in-group)
    const int slot = t & 31;                 // 16B slot within a row
    const char* rdp = smem + (size_t)rowl * 512
                    + (size_t)((slot ^ rowl) * 16);
    const bool colok = bcol * 128 + slot * 4 < NCLS;  // NCLS%4==0

    #pragma unroll
    for (int h = 0; h < 2; ++h) {
        if (wrow == h) {
            #pragma unroll
            for (int mi = 0; mi < 4; ++mi) {
                const int r = mi * 16 + lr;          // row in half (0..63)
                #pragma unroll
                for (int ni = 0; ni < 4; ++ni) {
                    const int s = wcol * 16 + ni * 4 + lg;
                    f32x4 v = acc[mi][ni];
                    f32x4 o;
                    #pragma unroll
                    for (int j = 0; j < 4; ++j) {
                        float cc = fminf(fmaxf(v[j], -1.0f + 1e-7f),
                                         1.0f - 1e-7f);
                        o[j] = cc * SCALE_;
                    }
                    *(f32x4*)(smem + (size_t)r * 512
                              + (size_t)((s ^ (r & 7)) * 16)) = o;
                }
            }
        }
        asm volatile("s_waitcnt lgkmcnt(0)" ::: "memory");
        __builtin_amdgcn_s_barrier();
        if (colok) {
            #pragma unroll
            for (int p = 0; p < 8; ++p) {
                f32x4 v = *(const f32x4*)(rdp + (size_t)p * 4096);
                const int grow = mbase + h * 64 + p * 8 + rowl;
                __builtin_nontemporal_store(v,
                    (f32x4*)((char*)C + (size_t)grow * (NCLS * 4)
                             + cb + (size_t)slot * 16));
            }
        }
        if (h == 0) {
            asm volatile("s_waitcnt lgkmcnt(0)" ::: "memory");
            __builtin_amdgcn_s_barrier();    // half-0 reads done before overwrite
        }
    }
#undef STAGE
#undef COMPUTE
}

extern "C" void kernel_launch(void* const* d_in, const int* in_sizes, int n_in,
                              void* d_out, int out_size, void* d_ws, size_t ws_size,
                              hipStream_t stream)
{
    const float* emb    = (const float*)d_in[0];
    const int*   labels = (const int*)d_in[1];
    const float* wgt    = (const float*)d_in[2];
    float*       out    = (float*)d_out;

    // workspace layout: [Ebf: 1024*512 bf16 = 1 MB][Wbf: 100096*512 bf16 = 102.5 MB]
    ushort* Ebf = (ushort*)d_ws;
    ushort* Wbf = (ushort*)((char*)d_ws + (size_t)BATCH * EDIM * 2);

    norm_all_kernel<<<(BATCH + NPAD) / 4, 256, 0, stream>>>(emb, wgt, Ebf, Wbf);

    gemm_arc_kernel<<<(BATCH / 128) * (NPAD / 128), 256, 0, stream>>>(Ebf, Wbf, out);

    fixup_labels_kernel<<<BATCH / 256, 256, 0, stream>>>(labels, out);
}

// Round 17
// 199.437 us; speedup vs baseline: 1.8123x; 1.0234x over previous
//
#include <hip/hip_runtime.h>
#include <hip/hip_bf16.h>

#define NCLS   100000
#define NPAD   100096   // 782 * 128
#define BATCH  1024
#define EDIM   512

#define COS_M_  0.8775825618903728f
#define SIN_M_  0.479425538604203f
#define TH_     (-0.8775825618903728f)
#define MM_     0.2397127693021015f
#define SCALE_  64.0f

typedef __attribute__((ext_vector_type(8))) short short8;
typedef __attribute__((ext_vector_type(4))) float f32x4;

__device__ __forceinline__ ushort f2bf(float f) {
    // round-to-nearest-even f32 -> bf16
    uint u = __float_as_uint(f);
    u += 0x7fffu + ((u >> 16) & 1u);
    return (ushort)(u >> 16);
}

// One 64-lane wave per row: L2-normalize 512 f32 -> 512 bf16.
// Handles BOTH inputs in one launch: global wave id gw < BATCH -> emb row,
// else W row gw-BATCH (rows >= NCLS zero-filled for N-padding).
__global__ __launch_bounds__(256) void norm_all_kernel(
    const float* __restrict__ emb, const float* __restrict__ wgt,
    ushort* __restrict__ Ebf, ushort* __restrict__ Wbf)
{
    int gw   = (int)((blockIdx.x * blockDim.x + threadIdx.x) >> 6);
    int lane = (int)(threadIdx.x & 63);
    const float* ip;
    ushort* op;
    if (gw < BATCH) {
        ip = emb + (size_t)gw * EDIM + lane * 8;
        op = Ebf + (size_t)gw * EDIM + lane * 8;
    } else {
        int wr = gw - BATCH;
        if (wr >= NPAD) return;
        op = Wbf + (size_t)wr * EDIM + lane * 8;
        if (wr >= NCLS) {
            uint4 z = make_uint4(0u, 0u, 0u, 0u);
            *(uint4*)op = z;
            return;
        }
        ip = wgt + (size_t)wr * EDIM + lane * 8;
    }
    float4 x0 = *(const float4*)ip;
    float4 x1 = *(const float4*)(ip + 4);
    float ss = x0.x*x0.x + x0.y*x0.y + x0.z*x0.z + x0.w*x0.w
             + x1.x*x1.x + x1.y*x1.y + x1.z*x1.z + x1.w*x1.w;
    #pragma unroll
    for (int off = 32; off; off >>= 1) ss += __shfl_xor(ss, off, 64);
    float inv = 1.0f / fmaxf(sqrtf(ss), 1e-12f);
    uint w0 = (uint)f2bf(x0.x*inv) | ((uint)f2bf(x0.y*inv) << 16);
    uint w1 = (uint)f2bf(x0.z*inv) | ((uint)f2bf(x0.w*inv) << 16);
    uint w2 = (uint)f2bf(x1.x*inv) | ((uint)f2bf(x1.y*inv) << 16);
    uint w3 = (uint)f2bf(x1.z*inv) | ((uint)f2bf(x1.w*inv) << 16);
    uint4 r; r.x = w0; r.y = w1; r.z = w2; r.w = w3;
    *(uint4*)op = r;
}

// Margin fixup: only the 1024 (row, label[row]) entries need the ArcFace
// margin. GEMM stored clamp(cos)*64; recover cos = v/64 (exact, pow2 scale),
// apply margin, rewrite.
__global__ __launch_bounds__(256) void fixup_labels_kernel(
    const int* __restrict__ labels, float* __restrict__ C)
{
    int row = (int)(blockIdx.x * blockDim.x + threadIdx.x);
    if (row >= BATCH) return;
    int lab = labels[row];
    float* p = C + (size_t)row * NCLS + lab;
    float c = *p * (1.0f / SCALE_);
    float s  = sqrtf(1.0f - c * c);
    float cm = c * COS_M_ - s * SIN_M_;
    cm = (c > TH_) ? cm : (c - MM_);
    *p = cm * SCALE_;
}

#define GLL16(g, s) __builtin_amdgcn_global_load_lds(                    \
    (const __attribute__((address_space(1))) void*)(g),                  \
    (__attribute__((address_space(3))) void*)(s), 16, 0, 0)

// 128x128 tile, BK=32, 4 waves (2x2), mfma_f32_16x16x32_bf16 (SWAPPED
// operands: lane's 4 acc regs = 4 consecutive N-cols). Depth-2 double-
// buffered LDS (32 KB -> 4 blocks/CU), counted vmcnt + raw s_barrier.
// XOR-swizzled K-slots, T1 XCD chunk swizzle. LDS-transposed epilogue —
// C half-tiles staged through the (now free) 32 KB LDS and NT-stored as
// fully line-covered contiguous 4 KB spans (kills the 1.42x partial-line
// write amplification of direct per-fragment NT stores; NT itself must stay:
// plain stores evict B panels from L2, +64us measured R10).
__global__ __launch_bounds__(256, 4) void gemm_arc_kernel(
    const ushort* __restrict__ A,
    const ushort* __restrict__ B,
    float* __restrict__ C)
{
    // A buffers at +0/+8192; B buffers at +16384/+24576. Reused as a
    // [64][128] f32 C-staging buffer (32 KB) in the epilogue.
    __shared__ __align__(16) char smem[32768];

    const int t    = (int)threadIdx.x;
    const int lane = t & 63;
    const int w    = t >> 6;
    const int wrow = w >> 1, wcol = w & 1;
    const int lr   = lane & 15, lg = lane >> 4;

    // T1 bijective XCD swizzle: the 8 M-blocks sharing a B-tile land on ONE
    // XCD. nwg = 6256, %8 == 0.
    const int nwg  = (int)gridDim.x;
    const int cpx  = nwg >> 3;               // 782
    const int bid  = (int)blockIdx.x;
    const int swz  = (bid & 7) * cpx + (bid >> 3);
    const int brow = swz & 7;                // M-tile (0..7)
    const int bcol = swz >> 3;               // N-tile (0..781)

    const f32x4 z4 = {0.f, 0.f, 0.f, 0.f};
    f32x4 acc[4][4];
    #pragma unroll
    for (int i = 0; i < 4; ++i)
        #pragma unroll
        for (int j = 0; j < 4; ++j) acc[i][j] = z4;

    // staging: 256 threads x 16 B = 4 KB per instruction = 64 rows x 64 B.
    // LDS dest linear; global SOURCE byte offset carries the inverse K-slot
    // swizzle off' ^= ((row>>1)&3)<<4.
    const int srow = t >> 2;
    const int scb  = ((t & 3) * 16) ^ (((t >> 3) & 3) << 4);
    const char* Ab = (const char*)(A + ((size_t)brow * 128 + srow) * EDIM) + scb;
    const char* Bb = (const char*)(B + ((size_t)bcol * 128 + srow) * EDIM) + scb;
    const uint ldsw = (uint)w * 1024;        // wave-uniform LDS base (+lane*16 HW)

    // ds_read side: row R, byte (lg*16) ^ ((R>>1)&3)<<4; for R = base16+lr the
    // XOR term is the per-lane constant ((lr>>1)&3)<<4.
    const int kswz  = ((lr >> 1) & 3) << 4;
    const int aoff0 = (wrow * 64 + lr) * 64 + ((lg * 16) ^ kswz);
    const int boff0 = (wcol * 64 + lr) * 64 + ((lg * 16) ^ kswz);

#define STAGE(c, kt) do {                                                  \
        const char* a0 = Ab + (kt) * 64;                                   \
        const char* b0 = Bb + (kt) * 64;                                   \
        char* Ad = smem + (size_t)(c) * 8192 + ldsw;                       \
        char* Bd = smem + 16384 + (size_t)(c) * 8192 + ldsw;               \
        GLL16(a0,                 Ad);                                     \
        GLL16(a0 + 64 * EDIM * 2, Ad + 4096);                              \
        GLL16(b0,                 Bd);                                     \
        GLL16(b0 + 64 * EDIM * 2, Bd + 4096);                              \
    } while (0)

// Swapped operands: mfma(bv, av) -> acc[mi][ni][reg] =
//   C[brow*128 + wrow*64 + mi*16 + lr][bcol*128 + wcol*64 + ni*16 + lg*4 + reg]
#define COMPUTE(c) do {                                                    \
        const char* Ap = (const char*)smem + (size_t)(c) * 8192;           \
        const char* Bp = (const char*)smem + 16384 + (size_t)(c) * 8192;   \
        short8 av[4], bv[4];                                               \
        _Pragma("unroll")                                                  \
        for (int mi = 0; mi < 4; ++mi)                                     \
            av[mi] = *(const short8*)(Ap + aoff0 + mi * 1024);             \
        _Pragma("unroll")                                                  \
        for (int ni = 0; ni < 4; ++ni)                                     \
            bv[ni] = *(const short8*)(Bp + boff0 + ni * 1024);             \
        _Pragma("unroll")                                                  \
        for (int mi = 0; mi < 4; ++mi)                                     \
            _Pragma("unroll")                                              \
            for (int ni = 0; ni < 4; ++ni)                                 \
                acc[mi][ni] = __builtin_amdgcn_mfma_f32_16x16x32_bf16(     \
                    bv[ni], av[mi], acc[mi][ni], 0, 0, 0);                 \
    } while (0)

    // prologue: stage tile 0 (4 loads in flight)
    STAGE(0, 0);

    // main loop: stage kt+1 into the other buffer, wait ONLY for tile kt
    // (vmcnt(4) leaves tile kt+1's 4 loads in flight across the barrier),
    // compute kt.
    #pragma unroll
    for (int kt = 0; kt < 15; ++kt) {
        asm volatile("s_waitcnt lgkmcnt(0)" ::: "memory");
        __builtin_amdgcn_s_barrier();
        STAGE((kt + 1) & 1, kt + 1);
        asm volatile("s_waitcnt vmcnt(4)" ::: "memory");
        __builtin_amdgcn_s_barrier();
        COMPUTE(kt & 1);
    }
    // tail: tile 15 already staged; drain
    asm volatile("s_waitcnt vmcnt(0)" ::: "memory");
    __builtin_amdgcn_s_barrier();
    COMPUTE(15 & 1);

    // ---- LDS-transposed epilogue ----
    // Half h = rows wrow==h (64 rows x 128 cols f32 = 32 KB). Waves of that
    // half ds_write clamp+scaled fragments at slot' = slot ^ (row&7)
    // (banks spread 8-way -> 2-way aliasing, free). All threads then read
    // back linearly and NT-store contiguous 4 KB per instruction (complete
    // 128-B lines -> no partial-line write amplification).
    asm volatile("s_waitcnt lgkmcnt(0)" ::: "memory");
    __builtin_amdgcn_s_barrier();            // all waves done with A/B LDS

    const int mbase = brow * 128;
    const size_t cb = (size_t)bcol * 512;    // C col byte base
    const int rowl = t >> 5;                 // 0..7 (readout row-in-group)
    const int slot = t & 31;                 // 16B slot within a row
    const char* rdp = smem + (size_t)rowl * 512
                    + (size_t)((slot ^ rowl) * 16);
    const bool colok = bcol * 128 + slot * 4 < NCLS;  // NCLS%4==0

    #pragma unroll
    for (int h = 0; h < 2; ++h) {
        if (wrow == h) {
            #pragma unroll
            for (int mi = 0; mi < 4; ++mi) {
                const int r = mi * 16 + lr;          // row in half (0..63)
                #pragma unroll
                for (int ni = 0; ni < 4; ++ni) {
                    const int s = wcol * 16 + ni * 4 + lg;
                    f32x4 v = acc[mi][ni];
                    f32x4 o;
                    #pragma unroll
                    for (int j = 0; j < 4; ++j) {
                        float cc = fminf(fmaxf(v[j], -1.0f + 1e-7f),
                                         1.0f - 1e-7f);
                        o[j] = cc * SCALE_;
                    }
                    *(f32x4*)(smem + (size_t)r * 512
                              + (size_t)((s ^ (r & 7)) * 16)) = o;
                }
            }
        }
        asm volatile("s_waitcnt lgkmcnt(0)" ::: "memory");
        __builtin_amdgcn_s_barrier();
        if (colok) {
            #pragma unroll
            for (int p = 0; p < 8; ++p) {
                f32x4 v = *(const f32x4*)(rdp + (size_t)p * 4096);
                const int grow = mbase + h * 64 + p * 8 + rowl;
                __builtin_nontemporal_store(v,
                    (f32x4*)((char*)C + (size_t)grow * (NCLS * 4)
                             + cb + (size_t)slot * 16));
            }
        }
        if (h == 0) {
            asm volatile("s_waitcnt lgkmcnt(0)" ::: "memory");
            __builtin_amdgcn_s_barrier();    // half-0 reads done before overwrite
        }
    }
#undef STAGE
#undef COMPUTE
}

extern "C" void kernel_launch(void* const* d_in, const int* in_sizes, int n_in,
                              void* d_out, int out_size, void* d_ws, size_t ws_size,
                              hipStream_t stream)
{
    const float* emb    = (const float*)d_in[0];
    const int*   labels = (const int*)d_in[1];
    const float* wgt    = (const float*)d_in[2];
    float*       out    = (float*)d_out;

    // workspace layout: [Ebf: 1024*512 bf16 = 1 MB][Wbf: 100096*512 bf16 = 102.5 MB]
    ushort* Ebf = (ushort*)d_ws;
    ushort* Wbf = (ushort*)((char*)d_ws + (size_t)BATCH * EDIM * 2);

    norm_all_kernel<<<(BATCH + NPAD) / 4, 256, 0, stream>>>(emb, wgt, Ebf, Wbf);

    gemm_arc_kernel<<<(BATCH / 128) * (NPAD / 128), 256, 0, stream>>>(Ebf, Wbf, out);

    fixup_labels_kernel<<<BATCH / 256, 256, 0, stream>>>(labels, out);
}